// Round 1
// baseline (878.611 us; speedup 1.0000x reference)
//
#include <hip/hip_runtime.h>
#include <hip/hip_bf16.h>

// Problem constants (from reference)
#define F_IN 64
#define HID 64
#define NCLS 10
#define NG 512

// ---------------------------------------------------------------------------
// GEMM1: x (N x 64) @ Wl1 (64 x 128) -> xl1 (N x 128), and @ Wr1 -> xr1.
// Block = 256 threads, 8 rows per block. Threads 0..127 -> Wl cols, 128..255 -> Wr cols.
__global__ void gemm1_kernel(const float* __restrict__ x,
                             const float* __restrict__ Wl,
                             const float* __restrict__ Wr,
                             float* __restrict__ xl, float* __restrict__ xr,
                             int N_) {
    __shared__ float xs[8 * 64];
    int r0 = blockIdx.x * 8;
    int t = threadIdx.x;
    for (int i = t; i < 8 * 64; i += 256) {
        int r = i >> 6;
        xs[i] = (r0 + r < N_) ? x[(long)(r0 + r) * 64 + (i & 63)] : 0.f;
    }
    __syncthreads();
    const float* W = (t < 128) ? Wl : Wr;
    int col = t & 127;
    float acc[8] = {0.f, 0.f, 0.f, 0.f, 0.f, 0.f, 0.f, 0.f};
    for (int k = 0; k < 64; ++k) {
        float w = W[k * 128 + col];
#pragma unroll
        for (int r = 0; r < 8; ++r) acc[r] += xs[r * 64 + k] * w;
    }
    float* out = (t < 128) ? xl : xr;
#pragma unroll
    for (int r = 0; r < 8; ++r)
        if (r0 + r < N_) out[(long)(r0 + r) * 128 + col] = acc[r];
}

// ---------------------------------------------------------------------------
// GEMM2: h1 (N x 128) @ Wl2 (128 x 64) -> xl2 (N x 64), and @ Wr2 -> xr2.
// Block = 128 threads, 8 rows per block.
__global__ void gemm2_kernel(const float* __restrict__ h1,
                             const float* __restrict__ Wl,
                             const float* __restrict__ Wr,
                             float* __restrict__ xl, float* __restrict__ xr,
                             int N_) {
    __shared__ float hs[8 * 128];
    int r0 = blockIdx.x * 8;
    int t = threadIdx.x;
    for (int i = t; i < 8 * 128; i += 128) {
        int r = i >> 7;
        hs[i] = (r0 + r < N_) ? h1[(long)(r0 + r) * 128 + (i & 127)] : 0.f;
    }
    __syncthreads();
    const float* W = (t < 64) ? Wl : Wr;
    int col = t & 63;
    float acc[8] = {0.f, 0.f, 0.f, 0.f, 0.f, 0.f, 0.f, 0.f};
    for (int k = 0; k < 128; ++k) {
        float w = W[k * 64 + col];
#pragma unroll
        for (int r = 0; r < 8; ++r) acc[r] += hs[r * 128 + k] * w;
    }
    float* out = (t < 64) ? xl : xr;
#pragma unroll
    for (int r = 0; r < 8; ++r)
        if (r0 + r < N_) out[(long)(r0 + r) * 64 + col] = acc[r];
}

// ---------------------------------------------------------------------------
// Edge pass layer 1 (H=2, C=64). One 64-lane wave per (edge, head).
// logit = att[h] . leaky_relu(xl[src,h,:] + xr[dst,h,:]); ex = exp(logit)
// (segment-max skipped: softmax is shift-invariant, logits are O(1)).
// denom[dst,h] += ex;  agg[dst,h,c] += ex * xl[src,h,c]
__global__ void edge1_kernel(const int* __restrict__ ei,
                             const float* __restrict__ xl,
                             const float* __restrict__ xr,
                             const float* __restrict__ att,
                             float* __restrict__ denom,
                             float* __restrict__ agg,
                             int E_, int N_) {
    long gid = (long)blockIdx.x * blockDim.x + threadIdx.x;
    int wid = (int)(gid >> 6);
    int lane = (int)(gid & 63);
    int total = (E_ + N_) * 2;
    if (wid >= total) return;
    int e = wid >> 1;
    int h = wid & 1;
    int s, d;
    if (e < E_) { s = ei[e]; d = ei[E_ + e]; }
    else        { s = e - E_; d = s; }
    float a  = xl[(long)s * 128 + h * 64 + lane];
    float bb = xr[(long)d * 128 + h * 64 + lane];
    float t = a + bb;
    t = (t >= 0.f) ? t : 0.2f * t;
    float p = att[h * 64 + lane] * t;
#pragma unroll
    for (int m = 1; m < 64; m <<= 1) p += __shfl_xor(p, m, 64);
    float ex = expf(p);
    if (lane == 0) atomicAdd(&denom[(long)d * 2 + h], ex);
    atomicAdd(&agg[(long)d * 128 + h * 64 + lane], ex * a);
}

// ---------------------------------------------------------------------------
// Edge pass layer 2 (H=1, C=64). One wave per edge.
__global__ void edge2_kernel(const int* __restrict__ ei,
                             const float* __restrict__ xl,
                             const float* __restrict__ xr,
                             const float* __restrict__ att,
                             float* __restrict__ denom,
                             float* __restrict__ agg,
                             int E_, int N_) {
    long gid = (long)blockIdx.x * blockDim.x + threadIdx.x;
    int wid = (int)(gid >> 6);
    int lane = (int)(gid & 63);
    int total = E_ + N_;
    if (wid >= total) return;
    int s, d;
    if (wid < E_) { s = ei[wid]; d = ei[E_ + wid]; }
    else          { s = wid - E_; d = s; }
    float a  = xl[(long)s * 64 + lane];
    float bb = xr[(long)d * 64 + lane];
    float t = a + bb;
    t = (t >= 0.f) ? t : 0.2f * t;
    float p = att[lane] * t;
#pragma unroll
    for (int m = 1; m < 64; m <<= 1) p += __shfl_xor(p, m, 64);
    float ex = expf(p);
    if (lane == 0) atomicAdd(&denom[d], ex);
    atomicAdd(&agg[(long)d * 64 + lane], ex * a);
}

// ---------------------------------------------------------------------------
// Node kernel 1: h1 = elu(agg/denom + b1), written in place over agg.
__global__ void node1_kernel(float* __restrict__ agg,
                             const float* __restrict__ denom,
                             const float* __restrict__ b1,
                             int N_) {
    long idx = (long)blockIdx.x * blockDim.x + threadIdx.x;
    if (idx >= (long)N_ * 128) return;
    int i = (int)(idx >> 7);
    int j = (int)(idx & 127);
    int h = j >> 6;
    float v = agg[idx] / denom[(long)i * 2 + h] + b1[j];
    agg[idx] = (v > 0.f) ? v : (expf(v) - 1.f);
}

// ---------------------------------------------------------------------------
// Node kernel 2 + pooling: h2 = agg/denom + b2; pooled[batch[i]] += h2; cnt += 1.
__global__ void node2_pool_kernel(const float* __restrict__ agg,
                                  const float* __restrict__ denom,
                                  const float* __restrict__ b2,
                                  const int* __restrict__ batch,
                                  float* __restrict__ pooled,
                                  float* __restrict__ cnt,
                                  int N_) {
    long idx = (long)blockIdx.x * blockDim.x + threadIdx.x;
    if (idx >= (long)N_ * 64) return;
    int i = (int)(idx >> 6);
    int c = (int)(idx & 63);
    float v = agg[idx] / denom[i] + b2[c];
    int g = batch[i];
    atomicAdd(&pooled[(long)g * 64 + c], v);
    if (c == 0) atomicAdd(&cnt[g], 1.0f);
}

// ---------------------------------------------------------------------------
// Final: out[g,k] = (pooled[g,:] / max(cnt,1)) @ lin_w + lin_b
__global__ void final_kernel(const float* __restrict__ pooled,
                             const float* __restrict__ cnt,
                             const float* __restrict__ lin_w,
                             const float* __restrict__ lin_b,
                             float* __restrict__ out) {
    int tid = blockIdx.x * blockDim.x + threadIdx.x;
    if (tid >= NG * NCLS) return;
    int g = tid / NCLS;
    int k = tid % NCLS;
    float inv = 1.0f / fmaxf(cnt[g], 1.0f);
    float acc = lin_b[k];
    for (int c = 0; c < 64; ++c)
        acc += pooled[g * 64 + c] * inv * lin_w[c * NCLS + k];
    out[tid] = acc;
}

// ---------------------------------------------------------------------------
extern "C" void kernel_launch(void* const* d_in, const int* in_sizes, int n_in,
                              void* d_out, int out_size, void* d_ws, size_t ws_size,
                              hipStream_t stream) {
    const float* x     = (const float*)d_in[0];
    const int*   ei    = (const int*)d_in[1];
    const int*   batch = (const int*)d_in[2];
    const float* Wl1   = (const float*)d_in[3];
    const float* Wr1   = (const float*)d_in[4];
    const float* att1  = (const float*)d_in[5];
    const float* b1    = (const float*)d_in[6];
    const float* Wl2   = (const float*)d_in[7];
    const float* Wr2   = (const float*)d_in[8];
    const float* att2  = (const float*)d_in[9];
    const float* b2    = (const float*)d_in[10];
    const float* lin_w = (const float*)d_in[11];
    const float* lin_b = (const float*)d_in[12];
    float* out = (float*)d_out;

    const int N_ = in_sizes[0] / F_IN;        // 50000
    const int E_ = in_sizes[1] / 2;           // 800000

    // Workspace layout (floats)
    float* ws = (float*)d_ws;
    float* A      = ws;                         // xl1 (N x 128); later xl2|xr2 (N x 64 each)
    float* B      = A + (long)N_ * 128;         // xr1 (N x 128)
    float* C      = B + (long)N_ * 128;         // agg1 -> h1 in place; later agg2 (N x 64)
    float* denom1 = C + (long)N_ * 128;         // N x 2
    float* denom2 = denom1 + (long)N_ * 2;      // N
    float* pooled = denom2 + N_;                // 512 x 64
    float* cnt    = pooled + NG * 64;           // 512
    float* xl2 = A;
    float* xr2 = A + (long)N_ * 64;
    float* agg2 = C;

    // 1. GEMM1: xl1, xr1
    gemm1_kernel<<<(N_ + 7) / 8, 256, 0, stream>>>(x, Wl1, Wr1, A, B, N_);

    // 2. zero agg1 + denom1
    hipMemsetAsync(C, 0, (size_t)N_ * 128 * sizeof(float), stream);
    hipMemsetAsync(denom1, 0, (size_t)N_ * 2 * sizeof(float), stream);

    // 3. edge pass 1
    {
        long waves = (long)(E_ + N_) * 2;
        long threads = waves * 64;
        int blocks = (int)((threads + 255) / 256);
        edge1_kernel<<<blocks, 256, 0, stream>>>(ei, A, B, att1, denom1, C, E_, N_);
    }

    // 4. node kernel 1: h1 in place in C
    {
        long total = (long)N_ * 128;
        node1_kernel<<<(int)((total + 255) / 256), 256, 0, stream>>>(C, denom1, b1, N_);
    }

    // 5. GEMM2: xl2, xr2 (into A)
    gemm2_kernel<<<(N_ + 7) / 8, 128, 0, stream>>>(C, Wl2, Wr2, xl2, xr2, N_);

    // 6. zero agg2 + denom2 (C is free after gemm2 consumed it... but agg2==C,
    //    so the memset must come after gemm2 reads C; stream order handles it)
    hipMemsetAsync(agg2, 0, (size_t)N_ * 64 * sizeof(float), stream);
    hipMemsetAsync(denom2, 0, (size_t)N_ * sizeof(float), stream);
    hipMemsetAsync(pooled, 0, (size_t)NG * 64 * sizeof(float), stream);
    hipMemsetAsync(cnt, 0, (size_t)NG * sizeof(float), stream);

    // 7. edge pass 2
    {
        long waves = (long)(E_ + N_);
        long threads = waves * 64;
        int blocks = (int)((threads + 255) / 256);
        edge2_kernel<<<blocks, 256, 0, stream>>>(ei, xl2, xr2, att2, denom2, agg2, E_, N_);
    }

    // 8. node kernel 2 + pooling
    {
        long total = (long)N_ * 64;
        node2_pool_kernel<<<(int)((total + 255) / 256), 256, 0, stream>>>(
            agg2, denom2, b2, batch, pooled, cnt, N_);
    }

    // 9. final classifier
    final_kernel<<<(NG * NCLS + 255) / 256, 256, 0, stream>>>(pooled, cnt, lin_w, lin_b, out);
}

// Round 2
// 599.043 us; speedup vs baseline: 1.4667x; 1.4667x over previous
//
#include <hip/hip_runtime.h>
#include <hip/hip_bf16.h>

#define F_IN 64
#define HID 64
#define NCLS 10
#define NG 512

// ---------------------------------------------------------------------------
// GEMM1: x (N x 64) @ Wl1 (64 x 128) -> xl1, @ Wr1 -> xr1.
__global__ void gemm1_kernel(const float* __restrict__ x,
                             const float* __restrict__ Wl,
                             const float* __restrict__ Wr,
                             float* __restrict__ xl, float* __restrict__ xr,
                             int N_) {
    __shared__ float xs[8 * 64];
    int r0 = blockIdx.x * 8;
    int t = threadIdx.x;
    for (int i = t; i < 8 * 64; i += 256) {
        int r = i >> 6;
        xs[i] = (r0 + r < N_) ? x[(long)(r0 + r) * 64 + (i & 63)] : 0.f;
    }
    __syncthreads();
    const float* W = (t < 128) ? Wl : Wr;
    int col = t & 127;
    float acc[8] = {0.f, 0.f, 0.f, 0.f, 0.f, 0.f, 0.f, 0.f};
    for (int k = 0; k < 64; ++k) {
        float w = W[k * 128 + col];
#pragma unroll
        for (int r = 0; r < 8; ++r) acc[r] += xs[r * 64 + k] * w;
    }
    float* out = (t < 128) ? xl : xr;
#pragma unroll
    for (int r = 0; r < 8; ++r)
        if (r0 + r < N_) out[(long)(r0 + r) * 128 + col] = acc[r];
}

// ---------------------------------------------------------------------------
// GEMM2: h1 (N x 128) @ Wl2 (128 x 64) -> xl2, @ Wr2 -> xr2.
__global__ void gemm2_kernel(const float* __restrict__ h1,
                             const float* __restrict__ Wl,
                             const float* __restrict__ Wr,
                             float* __restrict__ xl, float* __restrict__ xr,
                             int N_) {
    __shared__ float hs[8 * 128];
    int r0 = blockIdx.x * 8;
    int t = threadIdx.x;
    for (int i = t; i < 8 * 128; i += 128) {
        int r = i >> 7;
        hs[i] = (r0 + r < N_) ? h1[(long)(r0 + r) * 128 + (i & 127)] : 0.f;
    }
    __syncthreads();
    const float* W = (t < 64) ? Wl : Wr;
    int col = t & 63;
    float acc[8] = {0.f, 0.f, 0.f, 0.f, 0.f, 0.f, 0.f, 0.f};
    for (int k = 0; k < 128; ++k) {
        float w = W[k * 64 + col];
#pragma unroll
        for (int r = 0; r < 8; ++r) acc[r] += hs[r * 128 + k] * w;
    }
    float* out = (t < 64) ? xl : xr;
#pragma unroll
    for (int r = 0; r < 8; ++r)
        if (r0 + r < N_) out[(long)(r0 + r) * 64 + col] = acc[r];
}

// ---------------------------------------------------------------------------
// CSR build: deg count, single-block scan, scatter (src only; self-loops
// handled implicitly inside the gat kernels).
__global__ void count_kernel(const int* __restrict__ ei, int* __restrict__ deg, int E_) {
    int e = blockIdx.x * 256 + threadIdx.x;
    if (e < E_) atomicAdd(&deg[ei[E_ + e]], 1);
}

__global__ void scan_kernel(const int* __restrict__ deg, int* __restrict__ rs,
                            int* __restrict__ cursor, int N_) {
    __shared__ int part[1024];
    int t = threadIdx.x;
    int chunk = (N_ + 1023) >> 10;
    int lo = t * chunk, hi = min(lo + chunk, N_);
    int s = 0;
    for (int i = lo; i < hi; ++i) s += deg[i];
    part[t] = s;
    __syncthreads();
    for (int off = 1; off < 1024; off <<= 1) {
        int v = (t >= off) ? part[t - off] : 0;
        __syncthreads();
        part[t] += v;
        __syncthreads();
    }
    int run = part[t] - s;  // exclusive base
    for (int i = lo; i < hi; ++i) {
        rs[i] = run;
        cursor[i] = run;
        run += deg[i];
    }
    if (t == 1023) rs[N_] = part[1023];
}

__global__ void scatter_kernel(const int* __restrict__ ei, int* __restrict__ cursor,
                               int* __restrict__ csr_src, int E_) {
    int e = blockIdx.x * 256 + threadIdx.x;
    if (e < E_) {
        int d = ei[E_ + e];
        int pos = atomicAdd(&cursor[d], 1);
        csr_src[pos] = ei[e];
    }
}

// ---------------------------------------------------------------------------
// Fused GATv2 layer 1 (H=2, C=64): one wave per (node, head).
// For each in-edge: gather xl[src] row, logit via 64-lane butterfly,
// accumulate w*xl and w in registers. Fuses normalize + bias + ELU.
// Writes h1 in place over xr (each wave reads only its own xr row first).
__global__ void gat1_kernel(const float* __restrict__ xl,
                            float* __restrict__ xr,   // in: xr1, out: h1
                            const float* __restrict__ att,
                            const float* __restrict__ b1,
                            const int* __restrict__ rs,
                            const int* __restrict__ csr_src,
                            int N_) {
    int wid = (int)(((long)blockIdx.x * blockDim.x + threadIdx.x) >> 6);
    int lane = threadIdx.x & 63;
    if (wid >= N_ * 2) return;
    int d = wid >> 1, h = wid & 1;
    long rowoff = (long)d * 128 + h * 64 + lane;
    float xr_l = xr[rowoff];
    float att_l = att[h * 64 + lane];
    float bias = b1[h * 64 + lane];

    // self loop
    float a = xl[rowoff];
    float t = a + xr_l;
    t = (t >= 0.f) ? t : 0.2f * t;
    float p = att_l * t;
#pragma unroll
    for (int m = 1; m < 64; m <<= 1) p += __shfl_xor(p, m, 64);
    float w = __expf(p);
    float acc = w * a, den = w;

    int k = rs[d], k1 = rs[d + 1];
    int s_next = (k < k1) ? csr_src[k] : 0;
    while (k < k1) {
        int s = s_next;
        ++k;
        if (k < k1) s_next = csr_src[k];   // prefetch next src id
        float av = xl[(long)s * 128 + h * 64 + lane];
        float tt = av + xr_l;
        tt = (tt >= 0.f) ? tt : 0.2f * tt;
        float pp = att_l * tt;
#pragma unroll
        for (int m = 1; m < 64; m <<= 1) pp += __shfl_xor(pp, m, 64);
        float ww = __expf(pp);
        acc += ww * av;
        den += ww;
    }
    float v = acc / den + bias;
    xr[rowoff] = (v > 0.f) ? v : __expf(v) - 1.f;   // ELU
}

// ---------------------------------------------------------------------------
// Fused GATv2 layer 2 (H=1, C=64) + bias + mean-pool accumulation.
__global__ void gat2_pool_kernel(const float* __restrict__ xl,
                                 const float* __restrict__ xr,
                                 const float* __restrict__ att,
                                 const float* __restrict__ b2,
                                 const int* __restrict__ rs,
                                 const int* __restrict__ csr_src,
                                 const int* __restrict__ batch,
                                 float* __restrict__ pooled,
                                 float* __restrict__ cnt,
                                 int N_) {
    int d = (int)(((long)blockIdx.x * blockDim.x + threadIdx.x) >> 6);
    int lane = threadIdx.x & 63;
    if (d >= N_) return;
    long rowoff = (long)d * 64 + lane;
    float xr_l = xr[rowoff];
    float att_l = att[lane];

    float a = xl[rowoff];
    float t = a + xr_l;
    t = (t >= 0.f) ? t : 0.2f * t;
    float p = att_l * t;
#pragma unroll
    for (int m = 1; m < 64; m <<= 1) p += __shfl_xor(p, m, 64);
    float w = __expf(p);
    float acc = w * a, den = w;

    int k = rs[d], k1 = rs[d + 1];
    int s_next = (k < k1) ? csr_src[k] : 0;
    while (k < k1) {
        int s = s_next;
        ++k;
        if (k < k1) s_next = csr_src[k];
        float av = xl[(long)s * 64 + lane];
        float tt = av + xr_l;
        tt = (tt >= 0.f) ? tt : 0.2f * tt;
        float pp = att_l * tt;
#pragma unroll
        for (int m = 1; m < 64; m <<= 1) pp += __shfl_xor(pp, m, 64);
        float ww = __expf(pp);
        acc += ww * av;
        den += ww;
    }
    float v = acc / den + b2[lane];
    int g = batch[d];
    atomicAdd(&pooled[(long)g * 64 + lane], v);
    if (lane == 0) atomicAdd(&cnt[g], 1.0f);
}

// ---------------------------------------------------------------------------
__global__ void final_kernel(const float* __restrict__ pooled,
                             const float* __restrict__ cnt,
                             const float* __restrict__ lin_w,
                             const float* __restrict__ lin_b,
                             float* __restrict__ out) {
    int tid = blockIdx.x * blockDim.x + threadIdx.x;
    if (tid >= NG * NCLS) return;
    int g = tid / NCLS;
    int k = tid % NCLS;
    float inv = 1.0f / fmaxf(cnt[g], 1.0f);
    float acc = lin_b[k];
    for (int c = 0; c < 64; ++c)
        acc += pooled[g * 64 + c] * inv * lin_w[c * NCLS + k];
    out[tid] = acc;
}

// ---------------------------------------------------------------------------
extern "C" void kernel_launch(void* const* d_in, const int* in_sizes, int n_in,
                              void* d_out, int out_size, void* d_ws, size_t ws_size,
                              hipStream_t stream) {
    const float* x     = (const float*)d_in[0];
    const int*   ei    = (const int*)d_in[1];
    const int*   batch = (const int*)d_in[2];
    const float* Wl1   = (const float*)d_in[3];
    const float* Wr1   = (const float*)d_in[4];
    const float* att1  = (const float*)d_in[5];
    const float* b1    = (const float*)d_in[6];
    const float* Wl2   = (const float*)d_in[7];
    const float* Wr2   = (const float*)d_in[8];
    const float* att2  = (const float*)d_in[9];
    const float* b2    = (const float*)d_in[10];
    const float* lin_w = (const float*)d_in[11];
    const float* lin_b = (const float*)d_in[12];
    float* out = (float*)d_out;

    const int N_ = in_sizes[0] / F_IN;   // 50000
    const int E_ = in_sizes[1] / 2;      // 800000

    // Workspace layout
    float* ws = (float*)d_ws;
    float* A = ws;                        // xl1 (N x 128); later xl2|xr2
    float* B = A + (long)N_ * 128;        // xr1 -> h1 in place
    float* pooled = B + (long)N_ * 128;   // 512 x 64
    float* cnt = pooled + NG * 64;        // 512
    int* deg     = (int*)(cnt + NG);      // N
    int* rs      = deg + N_;              // N+1
    int* cursor  = rs + N_ + 1;           // N
    int* csr_src = cursor + N_;           // E
    float* xl2 = A;
    float* xr2 = A + (long)N_ * 64;

    // --- CSR build (once; reused by both layers) ---
    hipMemsetAsync(deg, 0, (size_t)N_ * sizeof(int), stream);
    count_kernel<<<(E_ + 255) / 256, 256, 0, stream>>>(ei, deg, E_);
    scan_kernel<<<1, 1024, 0, stream>>>(deg, rs, cursor, N_);
    scatter_kernel<<<(E_ + 255) / 256, 256, 0, stream>>>(ei, cursor, csr_src, E_);

    // --- layer 1 ---
    gemm1_kernel<<<(N_ + 7) / 8, 256, 0, stream>>>(x, Wl1, Wr1, A, B, N_);
    {
        long waves = (long)N_ * 2;
        int blocks = (int)((waves * 64 + 255) / 256);
        gat1_kernel<<<blocks, 256, 0, stream>>>(A, B, att1, b1, rs, csr_src, N_);
    }

    // --- layer 2 ---
    gemm2_kernel<<<(N_ + 7) / 8, 128, 0, stream>>>(B, Wl2, Wr2, xl2, xr2, N_);
    hipMemsetAsync(pooled, 0, (size_t)(NG * 64 + NG) * sizeof(float), stream);
    {
        int blocks = (int)(((long)N_ * 64 + 255) / 256);
        gat2_pool_kernel<<<blocks, 256, 0, stream>>>(xl2, xr2, att2, b2, rs, csr_src,
                                                     batch, pooled, cnt, N_);
    }

    // --- classifier ---
    final_kernel<<<(NG * NCLS + 255) / 256, 256, 0, stream>>>(pooled, cnt, lin_w, lin_b, out);
}

// Round 3
// 555.957 us; speedup vs baseline: 1.5804x; 1.0775x over previous
//
#include <hip/hip_runtime.h>
#include <hip/hip_bf16.h>

#define F_IN 64
#define HID 64
#define NCLS 10
#define NG 512

// ---------------------------------------------------------------------------
// GEMM1: x (N x 64) @ Wl1 (64 x 128) -> xl1, @ Wr1 -> xr1.
__global__ void gemm1_kernel(const float* __restrict__ x,
                             const float* __restrict__ Wl,
                             const float* __restrict__ Wr,
                             float* __restrict__ xl, float* __restrict__ xr,
                             int N_) {
    __shared__ float xs[8 * 64];
    int r0 = blockIdx.x * 8;
    int t = threadIdx.x;
    for (int i = t; i < 8 * 64; i += 256) {
        int r = i >> 6;
        xs[i] = (r0 + r < N_) ? x[(long)(r0 + r) * 64 + (i & 63)] : 0.f;
    }
    __syncthreads();
    const float* W = (t < 128) ? Wl : Wr;
    int col = t & 127;
    float acc[8] = {0.f, 0.f, 0.f, 0.f, 0.f, 0.f, 0.f, 0.f};
    for (int k = 0; k < 64; ++k) {
        float w = W[k * 128 + col];
#pragma unroll
        for (int r = 0; r < 8; ++r) acc[r] += xs[r * 64 + k] * w;
    }
    float* out = (t < 128) ? xl : xr;
#pragma unroll
    for (int r = 0; r < 8; ++r)
        if (r0 + r < N_) out[(long)(r0 + r) * 128 + col] = acc[r];
}

// ---------------------------------------------------------------------------
// GEMM2: h1 (N x 128) @ Wl2 (128 x 64) -> xl2, @ Wr2 -> xr2.
__global__ void gemm2_kernel(const float* __restrict__ h1,
                             const float* __restrict__ Wl,
                             const float* __restrict__ Wr,
                             float* __restrict__ xl, float* __restrict__ xr,
                             int N_) {
    __shared__ float hs[8 * 128];
    int r0 = blockIdx.x * 8;
    int t = threadIdx.x;
    for (int i = t; i < 8 * 128; i += 128) {
        int r = i >> 7;
        hs[i] = (r0 + r < N_) ? h1[(long)(r0 + r) * 128 + (i & 127)] : 0.f;
    }
    __syncthreads();
    const float* W = (t < 64) ? Wl : Wr;
    int col = t & 63;
    float acc[8] = {0.f, 0.f, 0.f, 0.f, 0.f, 0.f, 0.f, 0.f};
    for (int k = 0; k < 128; ++k) {
        float w = W[k * 64 + col];
#pragma unroll
        for (int r = 0; r < 8; ++r) acc[r] += hs[r * 128 + k] * w;
    }
    float* out = (t < 64) ? xl : xr;
#pragma unroll
    for (int r = 0; r < 8; ++r)
        if (r0 + r < N_) out[(long)(r0 + r) * 64 + col] = acc[r];
}

// ---------------------------------------------------------------------------
// CSR build
__global__ void count_kernel(const int* __restrict__ ei, int* __restrict__ deg, int E_) {
    int e = blockIdx.x * 256 + threadIdx.x;
    if (e < E_) atomicAdd(&deg[ei[E_ + e]], 1);
}

__global__ void scan_kernel(const int* __restrict__ deg, int* __restrict__ rs,
                            int* __restrict__ cursor, int N_) {
    __shared__ int part[1024];
    int t = threadIdx.x;
    int chunk = (N_ + 1023) >> 10;
    int lo = t * chunk, hi = min(lo + chunk, N_);
    int s = 0;
    for (int i = lo; i < hi; ++i) s += deg[i];
    part[t] = s;
    __syncthreads();
    for (int off = 1; off < 1024; off <<= 1) {
        int v = (t >= off) ? part[t - off] : 0;
        __syncthreads();
        part[t] += v;
        __syncthreads();
    }
    int run = part[t] - s;  // exclusive base
    for (int i = lo; i < hi; ++i) {
        rs[i] = run;
        cursor[i] = run;
        run += deg[i];
    }
    if (t == 1023) rs[N_] = part[1023];
}

__global__ void scatter_kernel(const int* __restrict__ ei, int* __restrict__ cursor,
                               int* __restrict__ csr_src, int E_) {
    int e = blockIdx.x * 256 + threadIdx.x;
    if (e < E_) {
        int d = ei[E_ + e];
        int pos = atomicAdd(&cursor[d], 1);
        csr_src[pos] = ei[e];
    }
}

// ---------------------------------------------------------------------------
// Fused GATv2 layer 1 (H=2, C=64): one wave per (node, head).
// Edge loop processes masked groups of 4 for memory-level parallelism:
// 4 row gathers in flight, 4 butterflies interleaved, invalid lanes -> w=0.
__global__ void gat1_kernel(const float* __restrict__ xl,
                            float* __restrict__ xr,   // in: xr1, out: h1
                            const float* __restrict__ att,
                            const float* __restrict__ b1,
                            const int* __restrict__ rs,
                            const int* __restrict__ csr_src,
                            int N_) {
    int wid = (int)(((long)blockIdx.x * blockDim.x + threadIdx.x) >> 6);
    int lane = threadIdx.x & 63;
    if (wid >= N_ * 2) return;
    int d = wid >> 1, h = wid & 1;
    long rowoff = (long)d * 128 + h * 64 + lane;
    float xr_l = xr[rowoff];
    float att_l = att[h * 64 + lane];

    // self loop
    float a = xl[rowoff];
    float t = a + xr_l;
    t = (t >= 0.f) ? t : 0.2f * t;
    float p = att_l * t;
#pragma unroll
    for (int m = 1; m < 64; m <<= 1) p += __shfl_xor(p, m, 64);
    float w = __expf(p);
    float acc = w * a, den = w;

    int k = rs[d], k1 = rs[d + 1];
    for (; k < k1; k += 4) {
        int n_v = k1 - k;  // valid count in this group (>=1)
        int s0 = csr_src[k];
        int s1 = (n_v > 1) ? csr_src[k + 1] : d;
        int s2 = (n_v > 2) ? csr_src[k + 2] : d;
        int s3 = (n_v > 3) ? csr_src[k + 3] : d;
        float a0 = xl[(long)s0 * 128 + h * 64 + lane];
        float a1 = xl[(long)s1 * 128 + h * 64 + lane];
        float a2 = xl[(long)s2 * 128 + h * 64 + lane];
        float a3 = xl[(long)s3 * 128 + h * 64 + lane];
        float t0 = a0 + xr_l; t0 = (t0 >= 0.f) ? t0 : 0.2f * t0;
        float t1 = a1 + xr_l; t1 = (t1 >= 0.f) ? t1 : 0.2f * t1;
        float t2 = a2 + xr_l; t2 = (t2 >= 0.f) ? t2 : 0.2f * t2;
        float t3 = a3 + xr_l; t3 = (t3 >= 0.f) ? t3 : 0.2f * t3;
        float p0 = att_l * t0, p1 = att_l * t1, p2 = att_l * t2, p3 = att_l * t3;
#pragma unroll
        for (int m = 1; m < 64; m <<= 1) {
            p0 += __shfl_xor(p0, m, 64);
            p1 += __shfl_xor(p1, m, 64);
            p2 += __shfl_xor(p2, m, 64);
            p3 += __shfl_xor(p3, m, 64);
        }
        float w0 = __expf(p0);
        float w1 = (n_v > 1) ? __expf(p1) : 0.f;
        float w2 = (n_v > 2) ? __expf(p2) : 0.f;
        float w3 = (n_v > 3) ? __expf(p3) : 0.f;
        acc += w0 * a0 + w1 * a1 + w2 * a2 + w3 * a3;
        den += w0 + w1 + w2 + w3;
    }
    float v = acc / den + b1[h * 64 + lane];
    xr[rowoff] = (v > 0.f) ? v : __expf(v) - 1.f;   // ELU
}

// ---------------------------------------------------------------------------
// Fused GATv2 layer 2 (H=1, C=64) + bias + mean-pool accumulation.
__global__ void gat2_pool_kernel(const float* __restrict__ xl,
                                 const float* __restrict__ xr,
                                 const float* __restrict__ att,
                                 const float* __restrict__ b2,
                                 const int* __restrict__ rs,
                                 const int* __restrict__ csr_src,
                                 const int* __restrict__ batch,
                                 float* __restrict__ pooled,
                                 float* __restrict__ cnt,
                                 int N_) {
    int d = (int)(((long)blockIdx.x * blockDim.x + threadIdx.x) >> 6);
    int lane = threadIdx.x & 63;
    if (d >= N_) return;
    long rowoff = (long)d * 64 + lane;
    float xr_l = xr[rowoff];
    float att_l = att[lane];

    float a = xl[rowoff];
    float t = a + xr_l;
    t = (t >= 0.f) ? t : 0.2f * t;
    float p = att_l * t;
#pragma unroll
    for (int m = 1; m < 64; m <<= 1) p += __shfl_xor(p, m, 64);
    float w = __expf(p);
    float acc = w * a, den = w;

    int k = rs[d], k1 = rs[d + 1];
    for (; k < k1; k += 4) {
        int n_v = k1 - k;
        int s0 = csr_src[k];
        int s1 = (n_v > 1) ? csr_src[k + 1] : d;
        int s2 = (n_v > 2) ? csr_src[k + 2] : d;
        int s3 = (n_v > 3) ? csr_src[k + 3] : d;
        float a0 = xl[(long)s0 * 64 + lane];
        float a1 = xl[(long)s1 * 64 + lane];
        float a2 = xl[(long)s2 * 64 + lane];
        float a3 = xl[(long)s3 * 64 + lane];
        float t0 = a0 + xr_l; t0 = (t0 >= 0.f) ? t0 : 0.2f * t0;
        float t1 = a1 + xr_l; t1 = (t1 >= 0.f) ? t1 : 0.2f * t1;
        float t2 = a2 + xr_l; t2 = (t2 >= 0.f) ? t2 : 0.2f * t2;
        float t3 = a3 + xr_l; t3 = (t3 >= 0.f) ? t3 : 0.2f * t3;
        float p0 = att_l * t0, p1 = att_l * t1, p2 = att_l * t2, p3 = att_l * t3;
#pragma unroll
        for (int m = 1; m < 64; m <<= 1) {
            p0 += __shfl_xor(p0, m, 64);
            p1 += __shfl_xor(p1, m, 64);
            p2 += __shfl_xor(p2, m, 64);
            p3 += __shfl_xor(p3, m, 64);
        }
        float w0 = __expf(p0);
        float w1 = (n_v > 1) ? __expf(p1) : 0.f;
        float w2 = (n_v > 2) ? __expf(p2) : 0.f;
        float w3 = (n_v > 3) ? __expf(p3) : 0.f;
        acc += w0 * a0 + w1 * a1 + w2 * a2 + w3 * a3;
        den += w0 + w1 + w2 + w3;
    }
    float v = acc / den + b2[lane];
    int g = batch[d];
    atomicAdd(&pooled[(long)g * 64 + lane], v);
    if (lane == 0) atomicAdd(&cnt[g], 1.0f);
}

// ---------------------------------------------------------------------------
__global__ void final_kernel(const float* __restrict__ pooled,
                             const float* __restrict__ cnt,
                             const float* __restrict__ lin_w,
                             const float* __restrict__ lin_b,
                             float* __restrict__ out) {
    int tid = blockIdx.x * blockDim.x + threadIdx.x;
    if (tid >= NG * NCLS) return;
    int g = tid / NCLS;
    int k = tid % NCLS;
    float inv = 1.0f / fmaxf(cnt[g], 1.0f);
    float acc = lin_b[k];
    for (int c = 0; c < 64; ++c)
        acc += pooled[g * 64 + c] * inv * lin_w[c * NCLS + k];
    out[tid] = acc;
}

// ---------------------------------------------------------------------------
extern "C" void kernel_launch(void* const* d_in, const int* in_sizes, int n_in,
                              void* d_out, int out_size, void* d_ws, size_t ws_size,
                              hipStream_t stream) {
    const float* x     = (const float*)d_in[0];
    const int*   ei    = (const int*)d_in[1];
    const int*   batch = (const int*)d_in[2];
    const float* Wl1   = (const float*)d_in[3];
    const float* Wr1   = (const float*)d_in[4];
    const float* att1  = (const float*)d_in[5];
    const float* b1    = (const float*)d_in[6];
    const float* Wl2   = (const float*)d_in[7];
    const float* Wr2   = (const float*)d_in[8];
    const float* att2  = (const float*)d_in[9];
    const float* b2    = (const float*)d_in[10];
    const float* lin_w = (const float*)d_in[11];
    const float* lin_b = (const float*)d_in[12];
    float* out = (float*)d_out;

    const int N_ = in_sizes[0] / F_IN;   // 50000
    const int E_ = in_sizes[1] / 2;      // 800000

    // Workspace layout
    float* ws = (float*)d_ws;
    float* A = ws;                        // xl1 (N x 128); later xl2|xr2
    float* B = A + (long)N_ * 128;        // xr1 -> h1 in place
    float* pooled = B + (long)N_ * 128;   // 512 x 64
    float* cnt = pooled + NG * 64;        // 512
    int* deg     = (int*)(cnt + NG);      // N
    int* rs      = deg + N_;              // N+1
    int* cursor  = rs + N_ + 1;           // N
    int* csr_src = cursor + N_;           // E
    float* xl2 = A;
    float* xr2 = A + (long)N_ * 64;

    // --- CSR build (once; reused by both layers) ---
    hipMemsetAsync(deg, 0, (size_t)N_ * sizeof(int), stream);
    count_kernel<<<(E_ + 255) / 256, 256, 0, stream>>>(ei, deg, E_);
    scan_kernel<<<1, 1024, 0, stream>>>(deg, rs, cursor, N_);
    scatter_kernel<<<(E_ + 255) / 256, 256, 0, stream>>>(ei, cursor, csr_src, E_);

    // --- layer 1 ---
    gemm1_kernel<<<(N_ + 7) / 8, 256, 0, stream>>>(x, Wl1, Wr1, A, B, N_);
    {
        long waves = (long)N_ * 2;
        int blocks = (int)((waves * 64 + 255) / 256);
        gat1_kernel<<<blocks, 256, 0, stream>>>(A, B, att1, b1, rs, csr_src, N_);
    }

    // --- layer 2 ---
    gemm2_kernel<<<(N_ + 7) / 8, 128, 0, stream>>>(B, Wl2, Wr2, xl2, xr2, N_);
    hipMemsetAsync(pooled, 0, (size_t)(NG * 64 + NG) * sizeof(float), stream);
    {
        int blocks = (int)(((long)N_ * 64 + 255) / 256);
        gat2_pool_kernel<<<blocks, 256, 0, stream>>>(xl2, xr2, att2, b2, rs, csr_src,
                                                     batch, pooled, cnt, N_);
    }

    // --- classifier ---
    final_kernel<<<(NG * NCLS + 255) / 256, 256, 0, stream>>>(pooled, cnt, lin_w, lin_b, out);
}

// Round 4
// 505.678 us; speedup vs baseline: 1.7375x; 1.0994x over previous
//
#include <hip/hip_runtime.h>
#include <hip/hip_bf16.h>

#define F_IN 64
#define HID 64
#define NCLS 10
#define NG 512

// ---------------------------------------------------------------------------
// GEMM1: x (N x 64) @ Wl1 (64 x 128) -> xl1, @ Wr1 -> xr1.
__global__ void gemm1_kernel(const float* __restrict__ x,
                             const float* __restrict__ Wl,
                             const float* __restrict__ Wr,
                             float* __restrict__ xl, float* __restrict__ xr,
                             int N_) {
    __shared__ float xs[8 * 64];
    int r0 = blockIdx.x * 8;
    int t = threadIdx.x;
    for (int i = t; i < 8 * 64; i += 256) {
        int r = i >> 6;
        xs[i] = (r0 + r < N_) ? x[(long)(r0 + r) * 64 + (i & 63)] : 0.f;
    }
    __syncthreads();
    const float* W = (t < 128) ? Wl : Wr;
    int col = t & 127;
    float acc[8] = {0.f, 0.f, 0.f, 0.f, 0.f, 0.f, 0.f, 0.f};
    for (int k = 0; k < 64; ++k) {
        float w = W[k * 128 + col];
#pragma unroll
        for (int r = 0; r < 8; ++r) acc[r] += xs[r * 64 + k] * w;
    }
    float* out = (t < 128) ? xl : xr;
#pragma unroll
    for (int r = 0; r < 8; ++r)
        if (r0 + r < N_) out[(long)(r0 + r) * 128 + col] = acc[r];
}

// ---------------------------------------------------------------------------
// GEMM2: h1 (N x 128) @ Wl2 (128 x 64) -> xl2, @ Wr2 -> xr2.
__global__ void gemm2_kernel(const float* __restrict__ h1,
                             const float* __restrict__ Wl,
                             const float* __restrict__ Wr,
                             float* __restrict__ xl, float* __restrict__ xr,
                             int N_) {
    __shared__ float hs[8 * 128];
    int r0 = blockIdx.x * 8;
    int t = threadIdx.x;
    for (int i = t; i < 8 * 128; i += 128) {
        int r = i >> 7;
        hs[i] = (r0 + r < N_) ? h1[(long)(r0 + r) * 128 + (i & 127)] : 0.f;
    }
    __syncthreads();
    const float* W = (t < 64) ? Wl : Wr;
    int col = t & 63;
    float acc[8] = {0.f, 0.f, 0.f, 0.f, 0.f, 0.f, 0.f, 0.f};
    for (int k = 0; k < 128; ++k) {
        float w = W[k * 64 + col];
#pragma unroll
        for (int r = 0; r < 8; ++r) acc[r] += hs[r * 128 + k] * w;
    }
    float* out = (t < 64) ? xl : xr;
#pragma unroll
    for (int r = 0; r < 8; ++r)
        if (r0 + r < N_) out[(long)(r0 + r) * 64 + col] = acc[r];
}

// ---------------------------------------------------------------------------
// CSR build
__global__ void count_kernel(const int* __restrict__ ei, int* __restrict__ deg, int E_) {
    int e = blockIdx.x * 256 + threadIdx.x;
    if (e < E_) atomicAdd(&deg[ei[E_ + e]], 1);
}

__global__ void scan_kernel(const int* __restrict__ deg, int* __restrict__ rs,
                            int* __restrict__ cursor, int N_) {
    __shared__ int part[1024];
    int t = threadIdx.x;
    int chunk = (N_ + 1023) >> 10;
    int lo = t * chunk, hi = min(lo + chunk, N_);
    int s = 0;
    for (int i = lo; i < hi; ++i) s += deg[i];
    part[t] = s;
    __syncthreads();
    for (int off = 1; off < 1024; off <<= 1) {
        int v = (t >= off) ? part[t - off] : 0;
        __syncthreads();
        part[t] += v;
        __syncthreads();
    }
    int run = part[t] - s;  // exclusive base
    for (int i = lo; i < hi; ++i) {
        rs[i] = run;
        cursor[i] = run;
        run += deg[i];
    }
    if (t == 1023) rs[N_] = part[1023];
}

__global__ void scatter_kernel(const int* __restrict__ ei, int* __restrict__ cursor,
                               int* __restrict__ csr_src, int E_) {
    int e = blockIdx.x * 256 + threadIdx.x;
    if (e < E_) {
        int d = ei[E_ + e];
        int pos = atomicAdd(&cursor[d], 1);
        csr_src[pos] = ei[e];
    }
}

// ---------------------------------------------------------------------------
// Fused GATv2 layer 1 (H=2, C=64): one wave per (node, head).
// Lane layout: 4 edge-groups x 16 lanes; each lane holds 4 channels (float4).
// Per 4-edge group: 1 float4 gather/lane, 4-step 16-lane butterfly shared by
// all 4 edges, ONE exp instruction for 4 edge weights. Self-loop = virtual
// edge at rs[d]-1 (group 0 of first iteration).
__global__ void gat1_kernel(const float* __restrict__ xl,
                            float* __restrict__ xr,   // in: xr1, out: h1
                            const float* __restrict__ att,
                            const float* __restrict__ b1,
                            const int* __restrict__ rs,
                            const int* __restrict__ csr_src,
                            int N_) {
    int wid = (int)(((long)blockIdx.x * blockDim.x + threadIdx.x) >> 6);
    int lane = threadIdx.x & 63;
    if (wid >= N_ * 2) return;
    int d = wid >> 1, h = wid & 1;
    int g = lane >> 4;        // edge slot 0..3
    int c4 = lane & 15;       // channel group: channels c4*4 .. c4*4+3
    long rowoff = (long)d * 128 + h * 64 + c4 * 4;
    const float4 xr4 = *(const float4*)(xr + rowoff);
    const float4 at4 = *(const float4*)(att + h * 64 + c4 * 4);

    float4 acc = make_float4(0.f, 0.f, 0.f, 0.f);
    float den = 0.f;
    int k0 = rs[d], k1 = rs[d + 1];
    for (int base = k0 - 1; base < k1; base += 4) {
        int idx = base + g;
        int s = d;                                   // self loop / masked default
        bool valid = (idx < k1);
        if (idx >= k0 && valid) s = csr_src[idx];
        float4 av = *(const float4*)(xl + (long)s * 128 + h * 64 + c4 * 4);
        float tx = av.x + xr4.x; tx = (tx >= 0.f) ? tx : 0.2f * tx;
        float ty = av.y + xr4.y; ty = (ty >= 0.f) ? ty : 0.2f * ty;
        float tz = av.z + xr4.z; tz = (tz >= 0.f) ? tz : 0.2f * tz;
        float tw = av.w + xr4.w; tw = (tw >= 0.f) ? tw : 0.2f * tw;
        float p = at4.x * tx + at4.y * ty + at4.z * tz + at4.w * tw;
        p += __shfl_xor(p, 1, 64);
        p += __shfl_xor(p, 2, 64);
        p += __shfl_xor(p, 4, 64);
        p += __shfl_xor(p, 8, 64);
        float w = valid ? __expf(p) : 0.f;
        acc.x += w * av.x; acc.y += w * av.y;
        acc.z += w * av.z; acc.w += w * av.w;
        den += w;
    }
#pragma unroll
    for (int m = 16; m < 64; m <<= 1) {
        acc.x += __shfl_xor(acc.x, m, 64);
        acc.y += __shfl_xor(acc.y, m, 64);
        acc.z += __shfl_xor(acc.z, m, 64);
        acc.w += __shfl_xor(acc.w, m, 64);
        den   += __shfl_xor(den, m, 64);
    }
    if (g == 0) {
        const float4 b4 = *(const float4*)(b1 + h * 64 + c4 * 4);
        float inv = 1.f / den;
        float4 v;
        v.x = acc.x * inv + b4.x; v.x = (v.x > 0.f) ? v.x : __expf(v.x) - 1.f;
        v.y = acc.y * inv + b4.y; v.y = (v.y > 0.f) ? v.y : __expf(v.y) - 1.f;
        v.z = acc.z * inv + b4.z; v.z = (v.z > 0.f) ? v.z : __expf(v.z) - 1.f;
        v.w = acc.w * inv + b4.w; v.w = (v.w > 0.f) ? v.w : __expf(v.w) - 1.f;
        *(float4*)(xr + rowoff) = v;   // h1 in place
    }
}

// ---------------------------------------------------------------------------
// Fused GATv2 layer 2 (H=1, C=64) + bias + mean-pool. Same lane layout.
__global__ void gat2_pool_kernel(const float* __restrict__ xl,
                                 const float* __restrict__ xr,
                                 const float* __restrict__ att,
                                 const float* __restrict__ b2,
                                 const int* __restrict__ rs,
                                 const int* __restrict__ csr_src,
                                 const int* __restrict__ batch,
                                 float* __restrict__ pooled,
                                 float* __restrict__ cnt,
                                 int N_) {
    int d = (int)(((long)blockIdx.x * blockDim.x + threadIdx.x) >> 6);
    int lane = threadIdx.x & 63;
    if (d >= N_) return;
    int g = lane >> 4;
    int c4 = lane & 15;
    long rowoff = (long)d * 64 + c4 * 4;
    const float4 xr4 = *(const float4*)(xr + rowoff);
    const float4 at4 = *(const float4*)(att + c4 * 4);

    float4 acc = make_float4(0.f, 0.f, 0.f, 0.f);
    float den = 0.f;
    int k0 = rs[d], k1 = rs[d + 1];
    for (int base = k0 - 1; base < k1; base += 4) {
        int idx = base + g;
        int s = d;
        bool valid = (idx < k1);
        if (idx >= k0 && valid) s = csr_src[idx];
        float4 av = *(const float4*)(xl + (long)s * 64 + c4 * 4);
        float tx = av.x + xr4.x; tx = (tx >= 0.f) ? tx : 0.2f * tx;
        float ty = av.y + xr4.y; ty = (ty >= 0.f) ? ty : 0.2f * ty;
        float tz = av.z + xr4.z; tz = (tz >= 0.f) ? tz : 0.2f * tz;
        float tw = av.w + xr4.w; tw = (tw >= 0.f) ? tw : 0.2f * tw;
        float p = at4.x * tx + at4.y * ty + at4.z * tz + at4.w * tw;
        p += __shfl_xor(p, 1, 64);
        p += __shfl_xor(p, 2, 64);
        p += __shfl_xor(p, 4, 64);
        p += __shfl_xor(p, 8, 64);
        float w = valid ? __expf(p) : 0.f;
        acc.x += w * av.x; acc.y += w * av.y;
        acc.z += w * av.z; acc.w += w * av.w;
        den += w;
    }
#pragma unroll
    for (int m = 16; m < 64; m <<= 1) {
        acc.x += __shfl_xor(acc.x, m, 64);
        acc.y += __shfl_xor(acc.y, m, 64);
        acc.z += __shfl_xor(acc.z, m, 64);
        acc.w += __shfl_xor(acc.w, m, 64);
        den   += __shfl_xor(den, m, 64);
    }
    const float4 b4 = *(const float4*)(b2 + c4 * 4);
    float inv = 1.f / den;
    float4 v;
    v.x = acc.x * inv + b4.x;
    v.y = acc.y * inv + b4.y;
    v.z = acc.z * inv + b4.z;
    v.w = acc.w * inv + b4.w;
    // every lane owns one distinct channel component: chan = c4*4 + g
    float comp = (g == 0) ? v.x : (g == 1) ? v.y : (g == 2) ? v.z : v.w;
    int gr = batch[d];
    atomicAdd(&pooled[(long)gr * 64 + c4 * 4 + g], comp);
    if (lane == 0) atomicAdd(&cnt[gr], 1.0f);
}

// ---------------------------------------------------------------------------
__global__ void final_kernel(const float* __restrict__ pooled,
                             const float* __restrict__ cnt,
                             const float* __restrict__ lin_w,
                             const float* __restrict__ lin_b,
                             float* __restrict__ out) {
    int tid = blockIdx.x * blockDim.x + threadIdx.x;
    if (tid >= NG * NCLS) return;
    int g = tid / NCLS;
    int k = tid % NCLS;
    float inv = 1.0f / fmaxf(cnt[g], 1.0f);
    float acc = lin_b[k];
    for (int c = 0; c < 64; ++c)
        acc += pooled[g * 64 + c] * inv * lin_w[c * NCLS + k];
    out[tid] = acc;
}

// ---------------------------------------------------------------------------
extern "C" void kernel_launch(void* const* d_in, const int* in_sizes, int n_in,
                              void* d_out, int out_size, void* d_ws, size_t ws_size,
                              hipStream_t stream) {
    const float* x     = (const float*)d_in[0];
    const int*   ei    = (const int*)d_in[1];
    const int*   batch = (const int*)d_in[2];
    const float* Wl1   = (const float*)d_in[3];
    const float* Wr1   = (const float*)d_in[4];
    const float* att1  = (const float*)d_in[5];
    const float* b1    = (const float*)d_in[6];
    const float* Wl2   = (const float*)d_in[7];
    const float* Wr2   = (const float*)d_in[8];
    const float* att2  = (const float*)d_in[9];
    const float* b2    = (const float*)d_in[10];
    const float* lin_w = (const float*)d_in[11];
    const float* lin_b = (const float*)d_in[12];
    float* out = (float*)d_out;

    const int N_ = in_sizes[0] / F_IN;   // 50000
    const int E_ = in_sizes[1] / 2;      // 800000

    // Workspace layout
    float* ws = (float*)d_ws;
    float* A = ws;                        // xl1 (N x 128); later xl2|xr2
    float* B = A + (long)N_ * 128;        // xr1 -> h1 in place
    float* pooled = B + (long)N_ * 128;   // 512 x 64
    float* cnt = pooled + NG * 64;        // 512
    int* deg     = (int*)(cnt + NG);      // N
    int* rs      = deg + N_;              // N+1
    int* cursor  = rs + N_ + 1;           // N
    int* csr_src = cursor + N_;           // E
    float* xl2 = A;
    float* xr2 = A + (long)N_ * 64;

    // --- CSR build (once; reused by both layers) ---
    hipMemsetAsync(deg, 0, (size_t)N_ * sizeof(int), stream);
    count_kernel<<<(E_ + 255) / 256, 256, 0, stream>>>(ei, deg, E_);
    scan_kernel<<<1, 1024, 0, stream>>>(deg, rs, cursor, N_);
    scatter_kernel<<<(E_ + 255) / 256, 256, 0, stream>>>(ei, cursor, csr_src, E_);

    // --- layer 1 ---
    gemm1_kernel<<<(N_ + 7) / 8, 256, 0, stream>>>(x, Wl1, Wr1, A, B, N_);
    {
        long waves = (long)N_ * 2;
        int blocks = (int)((waves * 64 + 255) / 256);
        gat1_kernel<<<blocks, 256, 0, stream>>>(A, B, att1, b1, rs, csr_src, N_);
    }

    // --- layer 2 ---
    gemm2_kernel<<<(N_ + 7) / 8, 128, 0, stream>>>(B, Wl2, Wr2, xl2, xr2, N_);
    hipMemsetAsync(pooled, 0, (size_t)(NG * 64 + NG) * sizeof(float), stream);
    {
        int blocks = (int)(((long)N_ * 64 + 255) / 256);
        gat2_pool_kernel<<<blocks, 256, 0, stream>>>(xl2, xr2, att2, b2, rs, csr_src,
                                                     batch, pooled, cnt, N_);
    }

    // --- classifier ---
    final_kernel<<<(NG * NCLS + 255) / 256, 256, 0, stream>>>(pooled, cnt, lin_w, lin_b, out);
}

// Round 5
// 495.162 us; speedup vs baseline: 1.7744x; 1.0212x over previous
//
#include <hip/hip_runtime.h>
#include <hip/hip_bf16.h>

#define F_IN 64
#define HID 64
#define NCLS 10
#define NG 512

// ---------------------------------------------------------------------------
// GEMM1: x (N x 64) @ Wl1 (64 x 128) -> xl1, @ Wr1 -> xr1.
__global__ void gemm1_kernel(const float* __restrict__ x,
                             const float* __restrict__ Wl,
                             const float* __restrict__ Wr,
                             float* __restrict__ xl, float* __restrict__ xr,
                             int N_) {
    __shared__ float xs[8 * 64];
    int r0 = blockIdx.x * 8;
    int t = threadIdx.x;
    for (int i = t; i < 8 * 64; i += 256) {
        int r = i >> 6;
        xs[i] = (r0 + r < N_) ? x[(long)(r0 + r) * 64 + (i & 63)] : 0.f;
    }
    __syncthreads();
    const float* W = (t < 128) ? Wl : Wr;
    int col = t & 127;
    float acc[8] = {0.f, 0.f, 0.f, 0.f, 0.f, 0.f, 0.f, 0.f};
    for (int k = 0; k < 64; ++k) {
        float w = W[k * 128 + col];
#pragma unroll
        for (int r = 0; r < 8; ++r) acc[r] += xs[r * 64 + k] * w;
    }
    float* out = (t < 128) ? xl : xr;
#pragma unroll
    for (int r = 0; r < 8; ++r)
        if (r0 + r < N_) out[(long)(r0 + r) * 128 + col] = acc[r];
}

// ---------------------------------------------------------------------------
// GEMM2: h1 (N x 128) @ Wl2 (128 x 64) -> xl2, @ Wr2 -> xr2.
__global__ void gemm2_kernel(const float* __restrict__ h1,
                             const float* __restrict__ Wl,
                             const float* __restrict__ Wr,
                             float* __restrict__ xl, float* __restrict__ xr,
                             int N_) {
    __shared__ float hs[8 * 128];
    int r0 = blockIdx.x * 8;
    int t = threadIdx.x;
    for (int i = t; i < 8 * 128; i += 128) {
        int r = i >> 7;
        hs[i] = (r0 + r < N_) ? h1[(long)(r0 + r) * 128 + (i & 127)] : 0.f;
    }
    __syncthreads();
    const float* W = (t < 64) ? Wl : Wr;
    int col = t & 63;
    float acc[8] = {0.f, 0.f, 0.f, 0.f, 0.f, 0.f, 0.f, 0.f};
    for (int k = 0; k < 128; ++k) {
        float w = W[k * 64 + col];
#pragma unroll
        for (int r = 0; r < 8; ++r) acc[r] += hs[r * 128 + k] * w;
    }
    float* out = (t < 64) ? xl : xr;
#pragma unroll
    for (int r = 0; r < 8; ++r)
        if (r0 + r < N_) out[(long)(r0 + r) * 64 + col] = acc[r];
}

// ---------------------------------------------------------------------------
// CSR build
__global__ void count_kernel(const int* __restrict__ ei, int* __restrict__ deg, int E_) {
    int e = blockIdx.x * 256 + threadIdx.x;
    if (e < E_) atomicAdd(&deg[ei[E_ + e]], 1);
}

__global__ void scan_kernel(const int* __restrict__ deg, int* __restrict__ rs,
                            int* __restrict__ cursor, int N_) {
    __shared__ int part[1024];
    int t = threadIdx.x;
    int chunk = (N_ + 1023) >> 10;
    int lo = t * chunk, hi = min(lo + chunk, N_);
    int s = 0;
    for (int i = lo; i < hi; ++i) s += deg[i];
    part[t] = s;
    __syncthreads();
    for (int off = 1; off < 1024; off <<= 1) {
        int v = (t >= off) ? part[t - off] : 0;
        __syncthreads();
        part[t] += v;
        __syncthreads();
    }
    int run = part[t] - s;  // exclusive base
    for (int i = lo; i < hi; ++i) {
        rs[i] = run;
        cursor[i] = run;
        run += deg[i];
    }
    if (t == 1023) rs[N_] = part[1023];
}

__global__ void scatter_kernel(const int* __restrict__ ei, int* __restrict__ cursor,
                               int* __restrict__ csr_src, int E_) {
    int e = blockIdx.x * 256 + threadIdx.x;
    if (e < E_) {
        int d = ei[E_ + e];
        int pos = atomicAdd(&cursor[d], 1);
        csr_src[pos] = ei[e];
    }
}

// ---------------------------------------------------------------------------
// Fused GATv2 layer 1 (H=2, C=64): one wave per (node, head).
// Lane layout: 4 edge-slots x 16 lanes; each lane holds 4 channels (float4).
// Index window: one coalesced load puts up to 64 virtual-edge src ids in
// registers (slot 0 = self loop); inner loop fetches ids via __shfl
// (register->register) and keeps 2 gathers (8 edges) in flight.
__global__ void gat1_kernel(const float* __restrict__ xl,
                            float* __restrict__ xr,   // in: xr1, out: h1
                            const float* __restrict__ att,
                            const float* __restrict__ b1,
                            const int* __restrict__ rs,
                            const int* __restrict__ csr_src,
                            int N_) {
    int wid = (int)(((long)blockIdx.x * blockDim.x + threadIdx.x) >> 6);
    int lane = threadIdx.x & 63;
    if (wid >= N_ * 2) return;
    int d = wid >> 1, h = wid & 1;
    int g = lane >> 4;        // edge slot 0..3
    int c4 = lane & 15;       // channel group
    long rowoff = (long)d * 128 + h * 64 + c4 * 4;
    const float4 xr4 = *(const float4*)(xr + rowoff);
    const float4 at4 = *(const float4*)(att + h * 64 + c4 * 4);

    int k0 = rs[d], k1 = rs[d + 1];
    int cnt = k1 - k0 + 1;    // virtual edges incl. self (slot 0)

    float4 acc = make_float4(0.f, 0.f, 0.f, 0.f);
    float den = 0.f;
    for (int c0 = 0; c0 < cnt; c0 += 64) {
        int wl = c0 + lane;   // virtual edge id held by this lane
        int myidx = (wl >= 1 && wl < cnt) ? csr_src[k0 + wl - 1] : d;
        int lim = min(64, cnt - c0);
        for (int p = 0; p < lim; p += 8) {
            int e0 = p + g, e1 = p + 4 + g;
            int s0 = __shfl(myidx, e0, 64);
            int s1 = __shfl(myidx, e1, 64);
            bool v0 = e0 < lim, v1 = e1 < lim;
            float4 a0 = *(const float4*)(xl + (long)s0 * 128 + h * 64 + c4 * 4);
            float4 a1 = *(const float4*)(xl + (long)s1 * 128 + h * 64 + c4 * 4);
            float t, p0, p1;
            t = a0.x + xr4.x; t = (t >= 0.f) ? t : 0.2f * t; p0  = at4.x * t;
            t = a0.y + xr4.y; t = (t >= 0.f) ? t : 0.2f * t; p0 += at4.y * t;
            t = a0.z + xr4.z; t = (t >= 0.f) ? t : 0.2f * t; p0 += at4.z * t;
            t = a0.w + xr4.w; t = (t >= 0.f) ? t : 0.2f * t; p0 += at4.w * t;
            t = a1.x + xr4.x; t = (t >= 0.f) ? t : 0.2f * t; p1  = at4.x * t;
            t = a1.y + xr4.y; t = (t >= 0.f) ? t : 0.2f * t; p1 += at4.y * t;
            t = a1.z + xr4.z; t = (t >= 0.f) ? t : 0.2f * t; p1 += at4.z * t;
            t = a1.w + xr4.w; t = (t >= 0.f) ? t : 0.2f * t; p1 += at4.w * t;
            p0 += __shfl_xor(p0, 1, 64);  p1 += __shfl_xor(p1, 1, 64);
            p0 += __shfl_xor(p0, 2, 64);  p1 += __shfl_xor(p1, 2, 64);
            p0 += __shfl_xor(p0, 4, 64);  p1 += __shfl_xor(p1, 4, 64);
            p0 += __shfl_xor(p0, 8, 64);  p1 += __shfl_xor(p1, 8, 64);
            float w0 = v0 ? __expf(p0) : 0.f;
            float w1 = v1 ? __expf(p1) : 0.f;
            acc.x += w0 * a0.x + w1 * a1.x;
            acc.y += w0 * a0.y + w1 * a1.y;
            acc.z += w0 * a0.z + w1 * a1.z;
            acc.w += w0 * a0.w + w1 * a1.w;
            den += w0 + w1;
        }
    }
#pragma unroll
    for (int m = 16; m < 64; m <<= 1) {
        acc.x += __shfl_xor(acc.x, m, 64);
        acc.y += __shfl_xor(acc.y, m, 64);
        acc.z += __shfl_xor(acc.z, m, 64);
        acc.w += __shfl_xor(acc.w, m, 64);
        den   += __shfl_xor(den, m, 64);
    }
    if (g == 0) {
        const float4 b4 = *(const float4*)(b1 + h * 64 + c4 * 4);
        float inv = 1.f / den;
        float4 v;
        v.x = acc.x * inv + b4.x; v.x = (v.x > 0.f) ? v.x : __expf(v.x) - 1.f;
        v.y = acc.y * inv + b4.y; v.y = (v.y > 0.f) ? v.y : __expf(v.y) - 1.f;
        v.z = acc.z * inv + b4.z; v.z = (v.z > 0.f) ? v.z : __expf(v.z) - 1.f;
        v.w = acc.w * inv + b4.w; v.w = (v.w > 0.f) ? v.w : __expf(v.w) - 1.f;
        *(float4*)(xr + rowoff) = v;   // h1 in place
    }
}

// ---------------------------------------------------------------------------
// Fused GATv2 layer 2 (H=1, C=64) + bias + mean-pool. Same structure.
__global__ void gat2_pool_kernel(const float* __restrict__ xl,
                                 const float* __restrict__ xr,
                                 const float* __restrict__ att,
                                 const float* __restrict__ b2,
                                 const int* __restrict__ rs,
                                 const int* __restrict__ csr_src,
                                 const int* __restrict__ batch,
                                 float* __restrict__ pooled,
                                 float* __restrict__ cnt_,
                                 int N_) {
    int d = (int)(((long)blockIdx.x * blockDim.x + threadIdx.x) >> 6);
    int lane = threadIdx.x & 63;
    if (d >= N_) return;
    int g = lane >> 4;
    int c4 = lane & 15;
    long rowoff = (long)d * 64 + c4 * 4;
    const float4 xr4 = *(const float4*)(xr + rowoff);
    const float4 at4 = *(const float4*)(att + c4 * 4);

    int k0 = rs[d], k1 = rs[d + 1];
    int cnt = k1 - k0 + 1;

    float4 acc = make_float4(0.f, 0.f, 0.f, 0.f);
    float den = 0.f;
    for (int c0 = 0; c0 < cnt; c0 += 64) {
        int wl = c0 + lane;
        int myidx = (wl >= 1 && wl < cnt) ? csr_src[k0 + wl - 1] : d;
        int lim = min(64, cnt - c0);
        for (int p = 0; p < lim; p += 8) {
            int e0 = p + g, e1 = p + 4 + g;
            int s0 = __shfl(myidx, e0, 64);
            int s1 = __shfl(myidx, e1, 64);
            bool v0 = e0 < lim, v1 = e1 < lim;
            float4 a0 = *(const float4*)(xl + (long)s0 * 64 + c4 * 4);
            float4 a1 = *(const float4*)(xl + (long)s1 * 64 + c4 * 4);
            float t, p0, p1;
            t = a0.x + xr4.x; t = (t >= 0.f) ? t : 0.2f * t; p0  = at4.x * t;
            t = a0.y + xr4.y; t = (t >= 0.f) ? t : 0.2f * t; p0 += at4.y * t;
            t = a0.z + xr4.z; t = (t >= 0.f) ? t : 0.2f * t; p0 += at4.z * t;
            t = a0.w + xr4.w; t = (t >= 0.f) ? t : 0.2f * t; p0 += at4.w * t;
            t = a1.x + xr4.x; t = (t >= 0.f) ? t : 0.2f * t; p1  = at4.x * t;
            t = a1.y + xr4.y; t = (t >= 0.f) ? t : 0.2f * t; p1 += at4.y * t;
            t = a1.z + xr4.z; t = (t >= 0.f) ? t : 0.2f * t; p1 += at4.z * t;
            t = a1.w + xr4.w; t = (t >= 0.f) ? t : 0.2f * t; p1 += at4.w * t;
            p0 += __shfl_xor(p0, 1, 64);  p1 += __shfl_xor(p1, 1, 64);
            p0 += __shfl_xor(p0, 2, 64);  p1 += __shfl_xor(p1, 2, 64);
            p0 += __shfl_xor(p0, 4, 64);  p1 += __shfl_xor(p1, 4, 64);
            p0 += __shfl_xor(p0, 8, 64);  p1 += __shfl_xor(p1, 8, 64);
            float w0 = v0 ? __expf(p0) : 0.f;
            float w1 = v1 ? __expf(p1) : 0.f;
            acc.x += w0 * a0.x + w1 * a1.x;
            acc.y += w0 * a0.y + w1 * a1.y;
            acc.z += w0 * a0.z + w1 * a1.z;
            acc.w += w0 * a0.w + w1 * a1.w;
            den += w0 + w1;
        }
    }
#pragma unroll
    for (int m = 16; m < 64; m <<= 1) {
        acc.x += __shfl_xor(acc.x, m, 64);
        acc.y += __shfl_xor(acc.y, m, 64);
        acc.z += __shfl_xor(acc.z, m, 64);
        acc.w += __shfl_xor(acc.w, m, 64);
        den   += __shfl_xor(den, m, 64);
    }
    const float4 b4 = *(const float4*)(b2 + c4 * 4);
    float inv = 1.f / den;
    float4 v;
    v.x = acc.x * inv + b4.x;
    v.y = acc.y * inv + b4.y;
    v.z = acc.z * inv + b4.z;
    v.w = acc.w * inv + b4.w;
    // each lane owns one distinct channel: chan = c4*4 + g
    float comp = (g == 0) ? v.x : (g == 1) ? v.y : (g == 2) ? v.z : v.w;
    int gr = batch[d];
    atomicAdd(&pooled[(long)gr * 64 + c4 * 4 + g], comp);
    if (lane == 0) atomicAdd(&cnt_[gr], 1.0f);
}

// ---------------------------------------------------------------------------
__global__ void final_kernel(const float* __restrict__ pooled,
                             const float* __restrict__ cnt,
                             const float* __restrict__ lin_w,
                             const float* __restrict__ lin_b,
                             float* __restrict__ out) {
    int tid = blockIdx.x * blockDim.x + threadIdx.x;
    if (tid >= NG * NCLS) return;
    int g = tid / NCLS;
    int k = tid % NCLS;
    float inv = 1.0f / fmaxf(cnt[g], 1.0f);
    float acc = lin_b[k];
    for (int c = 0; c < 64; ++c)
        acc += pooled[g * 64 + c] * inv * lin_w[c * NCLS + k];
    out[tid] = acc;
}

// ---------------------------------------------------------------------------
extern "C" void kernel_launch(void* const* d_in, const int* in_sizes, int n_in,
                              void* d_out, int out_size, void* d_ws, size_t ws_size,
                              hipStream_t stream) {
    const float* x     = (const float*)d_in[0];
    const int*   ei    = (const int*)d_in[1];
    const int*   batch = (const int*)d_in[2];
    const float* Wl1   = (const float*)d_in[3];
    const float* Wr1   = (const float*)d_in[4];
    const float* att1  = (const float*)d_in[5];
    const float* b1    = (const float*)d_in[6];
    const float* Wl2   = (const float*)d_in[7];
    const float* Wr2   = (const float*)d_in[8];
    const float* att2  = (const float*)d_in[9];
    const float* b2    = (const float*)d_in[10];
    const float* lin_w = (const float*)d_in[11];
    const float* lin_b = (const float*)d_in[12];
    float* out = (float*)d_out;

    const int N_ = in_sizes[0] / F_IN;   // 50000
    const int E_ = in_sizes[1] / 2;      // 800000

    // Workspace layout
    float* ws = (float*)d_ws;
    float* A = ws;                        // xl1 (N x 128); later xl2|xr2
    float* B = A + (long)N_ * 128;        // xr1 -> h1 in place
    float* pooled = B + (long)N_ * 128;   // 512 x 64
    float* cnt = pooled + NG * 64;        // 512
    int* deg     = (int*)(cnt + NG);      // N
    int* rs      = deg + N_;              // N+1
    int* cursor  = rs + N_ + 1;           // N
    int* csr_src = cursor + N_;           // E
    float* xl2 = A;
    float* xr2 = A + (long)N_ * 64;

    // --- CSR build (once; reused by both layers) ---
    hipMemsetAsync(deg, 0, (size_t)N_ * sizeof(int), stream);
    count_kernel<<<(E_ + 255) / 256, 256, 0, stream>>>(ei, deg, E_);
    scan_kernel<<<1, 1024, 0, stream>>>(deg, rs, cursor, N_);
    scatter_kernel<<<(E_ + 255) / 256, 256, 0, stream>>>(ei, cursor, csr_src, E_);

    // --- layer 1 ---
    gemm1_kernel<<<(N_ + 7) / 8, 256, 0, stream>>>(x, Wl1, Wr1, A, B, N_);
    {
        long waves = (long)N_ * 2;
        int blocks = (int)((waves * 64 + 255) / 256);
        gat1_kernel<<<blocks, 256, 0, stream>>>(A, B, att1, b1, rs, csr_src, N_);
    }

    // --- layer 2 ---
    gemm2_kernel<<<(N_ + 7) / 8, 128, 0, stream>>>(B, Wl2, Wr2, xl2, xr2, N_);
    hipMemsetAsync(pooled, 0, (size_t)(NG * 64 + NG) * sizeof(float), stream);
    {
        int blocks = (int)(((long)N_ * 64 + 255) / 256);
        gat2_pool_kernel<<<blocks, 256, 0, stream>>>(xl2, xr2, att2, b2, rs, csr_src,
                                                     batch, pooled, cnt, N_);
    }

    // --- classifier ---
    final_kernel<<<(NG * NCLS + 255) / 256, 256, 0, stream>>>(pooled, cnt, lin_w, lin_b, out);
}